// Round 3
// baseline (1068.722 us; speedup 1.0000x reference)
//
#include <hip/hip_runtime.h>
#include <hip/hip_bf16.h>
#include <cstdint>
#include <cstddef>

#define B_  256
#define Z_  512
#define H_  2048
#define T_  16
#define H3_ 6144
#define NWG 256

using short8 = __attribute__((ext_vector_type(8))) short;
using bf16x8 = __attribute__((ext_vector_type(8))) __bf16;
using f32x4  = __attribute__((ext_vector_type(4))) float;

__device__ __forceinline__ f32x4 mfma_bf16(short8 a, short8 b, f32x4 c) {
  return __builtin_amdgcn_mfma_f32_16x16x32_bf16(
      __builtin_bit_cast(bf16x8, a), __builtin_bit_cast(bf16x8, b), c, 0, 0, 0);
}

__device__ __forceinline__ unsigned short f2bf(float f) {
  unsigned int u = __builtin_bit_cast(unsigned int, f);
  u = (u + 0x7FFFu + ((u >> 16) & 1u)) >> 16;
  return (unsigned short)u;
}

__device__ __forceinline__ float sigmoidf_(float x) { return 1.0f / (1.0f + __expf(-x)); }

// LDS XOR swizzle: tiles are [rows][64] bf16 (128 B rows = 8x16B chunks).
__device__ __forceinline__ int swz(int row, int chunk) {
  return row * 64 + ((chunk ^ (row & 7)) << 3);   // ushort element offset
}

// Software grid barrier (sense reversal). All 256 WGs must be resident.
__device__ __forceinline__ void gbar(int* cnt, int* sense, int& ls) {
  __syncthreads();
  if (threadIdx.x == 0) {
    ls ^= 1;
    __threadfence();
    if (__hip_atomic_fetch_add(cnt, 1, __ATOMIC_ACQ_REL, __HIP_MEMORY_SCOPE_AGENT) == NWG - 1) {
      __hip_atomic_store(cnt, 0, __ATOMIC_RELAXED, __HIP_MEMORY_SCOPE_AGENT);
      __hip_atomic_store(sense, ls, __ATOMIC_RELEASE, __HIP_MEMORY_SCOPE_AGENT);
    } else {
      while (__hip_atomic_load(sense, __ATOMIC_ACQUIRE, __HIP_MEMORY_SCOPE_AGENT) != ls)
        __builtin_amdgcn_s_sleep(2);
    }
  }
  __syncthreads();
}

// ---------------------------------------------------------------------------
// 64x64 GEMM tile, C = A@B^T (*scale)(+add)(+bias). smem: sA 8KB, sB 8KB.
// ---------------------------------------------------------------------------
__device__ __forceinline__ void dev_gemm64(
    unsigned short* sA, unsigned short* sB,
    const unsigned short* __restrict__ A,
    const unsigned short* __restrict__ Bw, int K,
    const float* __restrict__ addsrc, int add_ld,
    const float* __restrict__ bias,
    const float* __restrict__ scale_ptr,
    unsigned short* __restrict__ out_bf,
    float* __restrict__ out_f, int ldo, int mi, int ni)
{
  const int tid = threadIdx.x;
  const int m0 = mi * 64, n0 = ni * 64;
  const int wave = tid >> 6, lane = tid & 63;
  const int wr = wave & 1, wc = wave >> 1;
  const int q = lane >> 4, c16 = lane & 15;
  const int lr = tid >> 3, lc8 = tid & 7;
  f32x4 acc[2][2] = {};
  const size_t aoff = (size_t)(m0 + lr) * K;
  const size_t boff = (size_t)(n0 + lr) * K;
  const size_t s32  = (size_t)32 * K;
  uint4 ra0, ra1, rb0, rb1;
  const int nIter = K >> 6;
  int gc = lc8 * 8;
  ra0 = *(const uint4*)(A  + aoff + gc);
  ra1 = *(const uint4*)(A  + aoff + s32 + gc);
  rb0 = *(const uint4*)(Bw + boff + gc);
  rb1 = *(const uint4*)(Bw + boff + s32 + gc);
  for (int it = 0; it < nIter; ++it) {
    __syncthreads();                      // LDS reuse guard
    *(uint4*)(sA + swz(lr, lc8))      = ra0;
    *(uint4*)(sA + swz(lr + 32, lc8)) = ra1;
    *(uint4*)(sB + swz(lr, lc8))      = rb0;
    *(uint4*)(sB + swz(lr + 32, lc8)) = rb1;
    __syncthreads();
    if (it + 1 < nIter) {
      gc = ((it + 1) << 6) + lc8 * 8;
      ra0 = *(const uint4*)(A  + aoff + gc);
      ra1 = *(const uint4*)(A  + aoff + s32 + gc);
      rb0 = *(const uint4*)(Bw + boff + gc);
      rb1 = *(const uint4*)(Bw + boff + s32 + gc);
    }
#pragma unroll
    for (int kk = 0; kk < 2; ++kk) {
      short8 af0 = *(const short8*)(sA + swz(wr * 32 + c16,      kk * 4 + q));
      short8 af1 = *(const short8*)(sA + swz(wr * 32 + 16 + c16, kk * 4 + q));
      short8 bf0 = *(const short8*)(sB + swz(wc * 32 + c16,      kk * 4 + q));
      short8 bf1 = *(const short8*)(sB + swz(wc * 32 + 16 + c16, kk * 4 + q));
      acc[0][0] = mfma_bf16(af0, bf0, acc[0][0]);
      acc[0][1] = mfma_bf16(af0, bf1, acc[0][1]);
      acc[1][0] = mfma_bf16(af1, bf0, acc[1][0]);
      acc[1][1] = mfma_bf16(af1, bf1, acc[1][1]);
    }
  }
  const float scale = scale_ptr ? *scale_ptr : 1.0f;
#pragma unroll
  for (int i = 0; i < 2; ++i)
#pragma unroll
    for (int j = 0; j < 2; ++j)
#pragma unroll
      for (int v = 0; v < 4; ++v) {
        const int row = m0 + wr * 32 + i * 16 + q * 4 + v;
        const int col = n0 + wc * 32 + j * 16 + c16;
        float val = acc[i][j][v] * scale;
        if (addsrc) val += addsrc[(size_t)row * add_ld + col];
        if (bias)   val += bias[col];
        if (out_f)  out_f[(size_t)row * ldo + col] = val;
        if (out_bf) out_bf[(size_t)row * ldo + col] = f2bf(val);
      }
}

// ---------------------------------------------------------------------------
// GRU tile: M=64 rows x (4 gates x 32 cols). smem: sA 8KB, sW 16KB.
// ---------------------------------------------------------------------------
__device__ __forceinline__ void dev_gru(
    unsigned short* sA, unsigned short* sW,
    const unsigned short* __restrict__ A, int K,
    const unsigned short* __restrict__ Wr,
    const unsigned short* __restrict__ Wz,
    const unsigned short* __restrict__ Wn,
    const unsigned short* __restrict__ Whn,
    const float* __restrict__ cr, const float* __restrict__ cz,
    const float* __restrict__ cn, const float* __restrict__ chn,
    float hn_scale,
    const float* __restrict__ h_old,
    float* __restrict__ h_new,
    unsigned short* __restrict__ h_hist,
    int m0, int n0)
{
  const int tid = threadIdx.x;
  const int wave = tid >> 6, lane = tid & 63;
  const int wr = wave & 1, wc = wave >> 1;
  const int q = lane >> 4, c16 = lane & 15;
  const int lr = tid >> 3, lc8 = tid & 7;
  f32x4 acc[4][2] = {};
  const size_t aoff = (size_t)(m0 + lr) * K;
  const size_t woff = (size_t)(n0 + lr) * K;
  const size_t a32  = (size_t)32 * K;
  uint4 ra0, ra1, rw0, rw1, rw2, rw3;
  const int nIter = K >> 6;
  int gc = lc8 * 8;
  ra0 = *(const uint4*)(A   + aoff + gc);
  ra1 = *(const uint4*)(A   + aoff + a32 + gc);
  rw0 = *(const uint4*)(Wr  + woff + gc);
  rw1 = *(const uint4*)(Wz  + woff + gc);
  rw2 = *(const uint4*)(Wn  + woff + gc);
  rw3 = *(const uint4*)(Whn + woff + gc);
  for (int it = 0; it < nIter; ++it) {
    __syncthreads();
    *(uint4*)(sA + swz(lr, lc8))        = ra0;
    *(uint4*)(sA + swz(lr + 32, lc8))   = ra1;
    *(uint4*)(sW + 0    + swz(lr, lc8)) = rw0;
    *(uint4*)(sW + 2048 + swz(lr, lc8)) = rw1;
    *(uint4*)(sW + 4096 + swz(lr, lc8)) = rw2;
    *(uint4*)(sW + 6144 + swz(lr, lc8)) = rw3;
    __syncthreads();
    if (it + 1 < nIter) {
      gc = ((it + 1) << 6) + lc8 * 8;
      ra0 = *(const uint4*)(A   + aoff + gc);
      ra1 = *(const uint4*)(A   + aoff + a32 + gc);
      rw0 = *(const uint4*)(Wr  + woff + gc);
      rw1 = *(const uint4*)(Wz  + woff + gc);
      rw2 = *(const uint4*)(Wn  + woff + gc);
      rw3 = *(const uint4*)(Whn + woff + gc);
    }
#pragma unroll
    for (int kk = 0; kk < 2; ++kk) {
      short8 af0 = *(const short8*)(sA + swz(wr * 32 + c16,      kk * 4 + q));
      short8 af1 = *(const short8*)(sA + swz(wr * 32 + 16 + c16, kk * 4 + q));
#pragma unroll
      for (int g = 0; g < 4; ++g) {
        short8 bf = *(const short8*)(sW + g * 2048 + swz(wc * 16 + c16, kk * 4 + q));
        acc[g][0] = mfma_bf16(af0, bf, acc[g][0]);
        acc[g][1] = mfma_bf16(af1, bf, acc[g][1]);
      }
    }
  }
#pragma unroll
  for (int i = 0; i < 2; ++i)
#pragma unroll
    for (int v = 0; v < 4; ++v) {
      const int row = m0 + wr * 32 + i * 16 + q * 4 + v;
      const int col = n0 + wc * 16 + c16;
      const float R   = sigmoidf_(acc[0][i][v] + cr[col]);
      const float U   = sigmoidf_(acc[1][i][v] + cz[col]);
      const float hnv = hn_scale * acc[3][i][v] + chn[col];
      const float Nv  = tanhf(acc[2][i][v] + cn[col] + R * hnv);
      const float ho  = h_old ? h_old[(size_t)row * H_ + col] : 0.0f;
      const float hv  = (1.0f - U) * Nv + U * ho;
      h_new[(size_t)row * H_ + col]  = hv;
      h_hist[(size_t)row * H_ + col] = f2bf(hv);
    }
}

__global__ void initk(int* cnt, int* sense) {
  if (threadIdx.x == 0) { *cnt = 0; *sense = 0; }
}

// ---------------------------------------------------------------------------
// Persistent mega-kernel: all phases, grid barriers between.
// ---------------------------------------------------------------------------
__global__ __launch_bounds__(256, 1) void mega(
    const float* __restrict__ z, const float* __restrict__ fc_w,
    const float* __restrict__ fc_b, const float* __restrict__ fc_u,
    const float* __restrict__ w_ih, const float* __restrict__ w_hh,
    const float* __restrict__ b_ih, const float* __restrict__ b_hh,
    const float* __restrict__ lin_w, const float* __restrict__ lin_b,
    unsigned short* w_ih_q, unsigned short* w_hhn_q, unsigned short* lin_w_q,
    unsigned short* lin_wT_q, unsigned short* fc_w_q, unsigned short* z_q,
    unsigned short* x0_q, unsigned short* Wsum_r, unsigned short* Wsum_z,
    unsigned short* Wn_c, unsigned short* Hhist, float* h_f32,
    float* outs, float* c0r, float* c0z, float* c0n, float* c1r, float* c1z,
    float* c1n, float* chn, float* dvec, float* sig_tmp, float* invsig,
    float* out, int* bar_cnt, int* bar_sense)
{
  __shared__ __align__(16) unsigned char SMEM[24576];
  unsigned short* sAg = (unsigned short*)SMEM;          // 8KB
  unsigned short* sWg = (unsigned short*)(SMEM + 8192); // 16KB (4x4KB) / sB 8KB
  const int bid = blockIdx.x, tid = threadIdx.x;
  int ls = 0;

  // ---------------- Phase A: quant + transpose + dots -----------------------
  {
    const int gtid = bid * 256 + tid;
    // float4 ranges: z 32768 | fc_w 65536 | w_ih 786432 | w_hhn 1048576 | lin_w 262144
    for (int i = gtid; i < 2195456; i += NWG * 256) {
      const float4* src; ushort4* dst; int idx;
      if (i < 32768)        { src = (const float4*)z;     dst = (ushort4*)z_q;     idx = i; }
      else if (i < 98304)   { src = (const float4*)fc_w;  dst = (ushort4*)fc_w_q;  idx = i - 32768; }
      else if (i < 884736)  { src = (const float4*)w_ih;  dst = (ushort4*)w_ih_q;  idx = i - 98304; }
      else if (i < 1933312) { src = (const float4*)(w_hh + (size_t)2 * H_ * H_);
                              dst = (ushort4*)w_hhn_q;    idx = i - 884736; }
      else                  { src = (const float4*)lin_w; dst = (ushort4*)lin_w_q; idx = i - 1933312; }
      float4 v = src[idx];
      ushort4 o; o.x = f2bf(v.x); o.y = f2bf(v.y); o.z = f2bf(v.z); o.w = f2bf(v.w);
      dst[idx] = o;
    }
    // transq: lin_w [512][2048] -> lin_wT_q [2048][512] bf16, 1024 tiles
    float* tile = (float*)SMEM;  // [32][33]
    const int tx = tid & 31, ty = tid >> 5;
    for (int tt = bid; tt < 1024; tt += NWG) {
      const int bx = tt >> 4, by = tt & 15;
      const int k0 = bx * 32, z0 = by * 32;
      __syncthreads();
#pragma unroll
      for (int j = 0; j < 4; ++j)
        tile[(ty + j * 8) * 33 + tx] = lin_w[(size_t)(z0 + ty + j * 8) * H_ + k0 + tx];
      __syncthreads();
#pragma unroll
      for (int j = 0; j < 4; ++j)
        lin_wT_q[(size_t)(k0 + ty + j * 8) * Z_ + z0 + tx] = f2bf(tile[tx * 33 + ty + j * 8]);
    }
    // dots: dvec[row] = dot(w_ih[row], lin_b), 6144 rows over 1024 waves
    const int wave = tid >> 6, lane = tid & 63;
    const int wgid = bid * 4 + wave;
    for (int row = wgid; row < H3_; row += 1024) {
      float s = 0.f;
      for (int c = lane; c < Z_; c += 64) s += w_ih[(size_t)row * Z_ + c] * lin_b[c];
#pragma unroll
      for (int off = 32; off > 0; off >>= 1) s += __shfl_down(s, off);
      if (lane == 0) dvec[row] = s;
    }
  }
  gbar(bar_cnt, bar_sense, ls);

  // ---------------- Phase B: WG0 sigma chain || Wsum GEMMs + consts ---------
  if (bid == 0) {
    float* red = (float*)SMEM;
    float a0 = 0.f, a1 = 0.f;
    for (int r = 0; r < Z_; ++r) {
      const float uv = fc_u[r];
      const float* Wr_ = fc_w + (size_t)r * Z_;
      a0 += Wr_[2 * tid] * uv; a1 += Wr_[2 * tid + 1] * uv;
    }
    sig_tmp[2 * tid] = a0; sig_tmp[2 * tid + 1] = a1;
    red[tid] = a0 * a0 + a1 * a1;
    __syncthreads();
    for (int s = 128; s > 0; s >>= 1) { if (tid < s) red[tid] += red[tid + s]; __syncthreads(); }
    const float invn = 1.0f / (sqrtf(red[0]) + 1e-12f);
    __syncthreads();
    float b0 = 0.f, b1 = 0.f;
    for (int c = 0; c < Z_; ++c) {
      const float t1c = sig_tmp[c];
      b0 += fc_w[(size_t)(2 * tid) * Z_ + c] * t1c;
      b1 += fc_w[(size_t)(2 * tid + 1) * Z_ + c] * t1c;
    }
    b0 *= invn; b1 *= invn;
    red[tid] = b0 * b0 + b1 * b1;
    __syncthreads();
    for (int s = 128; s > 0; s >>= 1) { if (tid < s) red[tid] += red[tid + s]; __syncthreads(); }
    if (tid == 0) {
      const float s2 = red[0];
      const float sig = s2 / (sqrtf(s2) + 1e-12f);
      invsig[0] = 1.0f / sig;
    }
  } else {
    for (int j = bid - 1; j < 3080; j += NWG - 1) {
      if (j < 3072) {
        const int g = j >> 10, tt = j & 1023, mi = tt >> 5, ni = tt & 31;
        const float* adds = (g < 2) ? (w_hh + (size_t)g * H_ * H_) : nullptr;
        unsigned short* outw = (g == 0) ? Wsum_r : (g == 1) ? Wsum_z : Wn_c;
        dev_gemm64(sAg, sWg, w_ih_q + (size_t)g * H_ * Z_, lin_wT_q, Z_,
                   adds, H_, nullptr, nullptr, outw, nullptr, H_, mi, ni);
      } else {
        const int jj = (j - 3072) * 256 + tid;
        const float br = b_ih[jj], bz = b_ih[H_ + jj], bn = b_ih[2 * H_ + jj];
        const float hr = b_hh[jj], hz = b_hh[H_ + jj], hn = b_hh[2 * H_ + jj];
        c0r[jj] = br + hr; c0z[jj] = bz + hz; c0n[jj] = bn; chn[jj] = hn;
        c1r[jj] = br + hr + dvec[jj];
        c1z[jj] = bz + hz + dvec[H_ + jj];
        c1n[jj] = bn + dvec[2 * H_ + jj];
      }
    }
  }
  gbar(bar_cnt, bar_sense, ls);

  // ---------------- Phase C: x0 = (z @ fc_w^T)*invsig + fc_b ----------------
  if (bid < 32) {
    const int mi = bid >> 3, ni = bid & 7;
    dev_gemm64(sAg, sWg, z_q, fc_w_q, Z_, nullptr, 0, fc_b, invsig,
               x0_q, nullptr, Z_, mi, ni);
  }
  gbar(bar_cnt, bar_sense, ls);

  // ---------------- Phase D: 16 GRU steps -----------------------------------
  {
    const int xcd = bid & 7, rest = bid >> 3;
    const int m_idx = rest & 3, grp = rest >> 2;
    const int n_idx = grp * 8 + xcd;
    const int m0 = m_idx * 64, n0 = n_idx * 32;
#pragma unroll 1
    for (int t = 0; t < T_; ++t) {
      const bool first = (t == 0);
      const unsigned short* Aq = first ? x0_q : (Hhist + (size_t)(t - 1) * B_ * H_);
      const int K = first ? Z_ : H_;
      const unsigned short* Wr = first ? w_ih_q : Wsum_r;
      const unsigned short* Wz = first ? (w_ih_q + (size_t)H_ * Z_) : Wsum_z;
      const unsigned short* Wn = first ? (w_ih_q + (size_t)2 * H_ * Z_) : Wn_c;
      const unsigned short* Wh = first ? w_ih_q : w_hhn_q;
      const float* pcr = first ? c0r : c1r;
      const float* pcz = first ? c0z : c1z;
      const float* pcn = first ? c0n : c1n;
      const float hscale = first ? 0.0f : 1.0f;
      const float* hold = first ? nullptr : (h_f32 + (size_t)((t - 1) & 1) * B_ * H_);
      float* hnew = h_f32 + (size_t)(t & 1) * B_ * H_;
      unsigned short* hh = Hhist + (size_t)t * B_ * H_;
      dev_gru(sAg, sWg, Aq, K, Wr, Wz, Wn, Wh, pcr, pcz, pcn, chn,
              hscale, hold, hnew, hh, m0, n0);
      gbar(bar_cnt, bar_sense, ls);
    }
  }

  // ---------------- Phase E: outs = Hhist @ lin_w^T + lin_b -----------------
#pragma unroll 1
  for (int j = bid; j < 512; j += NWG) {
    const int mi = j >> 3, ni = j & 7;
    dev_gemm64(sAg, sWg, Hhist, lin_w_q, H_, nullptr, 0, lin_b, nullptr,
               nullptr, outs, Z_, mi, ni);
  }
  gbar(bar_cnt, bar_sense, ls);

  // ---------------- Phase F: BN over batch + transpose ----------------------
  if (bid < 128) {
    float* s_sum  = (float*)SMEM;        // [4][64]
    float* s_sq   = s_sum + 256;         // [4][64]
    float* s_mean = s_sq + 256;          // [64]
    float* s_inv  = s_mean + 64;         // [64]
    const int t = bid >> 3, zb = bid & 7;
    const int zl = tid & 63, bp = tid >> 6;
    const int zc = zb * 64 + zl;
    float sum = 0.f, sq = 0.f;
    for (int b = bp * 64; b < bp * 64 + 64; ++b) {
      float v = outs[(size_t)(t * 256 + b) * Z_ + zc];
      sum += v; sq += v * v;
    }
    s_sum[bp * 64 + zl] = sum; s_sq[bp * 64 + zl] = sq;
    __syncthreads();
    if (bp == 0) {
      float S = s_sum[zl] + s_sum[64 + zl] + s_sum[128 + zl] + s_sum[192 + zl];
      float Q = s_sq[zl] + s_sq[64 + zl] + s_sq[128 + zl] + s_sq[192 + zl];
      float mean = S * (1.0f / 256.0f);
      float var  = Q * (1.0f / 256.0f) - mean * mean;
      s_mean[zl] = mean;
      s_inv[zl]  = rsqrtf(var + 1e-5f);
    }
    __syncthreads();
    const float mean = s_mean[zl], inv = s_inv[zl];
    for (int b = bp * 64; b < bp * 64 + 64; ++b) {
      float v = outs[(size_t)(t * 256 + b) * Z_ + zc];
      out[(size_t)(b * T_ + t) * Z_ + zc] = (v - mean) * inv;
    }
  }
}

// ---------------------------------------------------------------------------
extern "C" void kernel_launch(void* const* d_in, const int* in_sizes, int n_in,
                              void* d_out, int out_size, void* d_ws, size_t ws_size,
                              hipStream_t stream) {
  const float* z     = (const float*)d_in[0];
  const float* fc_w  = (const float*)d_in[1];
  const float* fc_b  = (const float*)d_in[2];
  const float* fc_u  = (const float*)d_in[3];
  const float* w_ih  = (const float*)d_in[4];
  const float* w_hh  = (const float*)d_in[5];
  const float* b_ih  = (const float*)d_in[6];
  const float* b_hh  = (const float*)d_in[7];
  const float* lin_w = (const float*)d_in[8];
  const float* lin_b = (const float*)d_in[9];
  float* out = (float*)d_out;

  char* ws = (char*)d_ws;
  size_t off = 0;
  auto alloc = [&](size_t bytes) -> void* {
    off = (off + 255) & ~(size_t)255;
    void* p = ws + off;
    off += bytes;
    return p;
  };
  unsigned short* w_ih_q   = (unsigned short*)alloc((size_t)H3_ * Z_ * 2);
  unsigned short* w_hhn_q  = (unsigned short*)alloc((size_t)H_ * H_ * 2);
  unsigned short* lin_w_q  = (unsigned short*)alloc((size_t)Z_ * H_ * 2);
  unsigned short* lin_wT_q = (unsigned short*)alloc((size_t)Z_ * H_ * 2);
  unsigned short* fc_w_q   = (unsigned short*)alloc((size_t)Z_ * Z_ * 2);
  unsigned short* z_q      = (unsigned short*)alloc((size_t)B_ * Z_ * 2);
  unsigned short* x0_q     = (unsigned short*)alloc((size_t)B_ * Z_ * 2);
  unsigned short* Wsum_r   = (unsigned short*)alloc((size_t)H_ * H_ * 2);
  unsigned short* Wsum_z   = (unsigned short*)alloc((size_t)H_ * H_ * 2);
  unsigned short* Wn_c     = (unsigned short*)alloc((size_t)H_ * H_ * 2);
  unsigned short* Hhist    = (unsigned short*)alloc((size_t)T_ * B_ * H_ * 2);
  float* h_f32 = (float*)alloc((size_t)2 * B_ * H_ * 4);
  float* outs  = (float*)alloc((size_t)T_ * B_ * Z_ * 4);
  float* c0r = (float*)alloc(H_ * 4);
  float* c0z = (float*)alloc(H_ * 4);
  float* c0n = (float*)alloc(H_ * 4);
  float* c1r = (float*)alloc(H_ * 4);
  float* c1z = (float*)alloc(H_ * 4);
  float* c1n = (float*)alloc(H_ * 4);
  float* chn = (float*)alloc(H_ * 4);
  float* dvec = (float*)alloc(H3_ * 4);
  float* sig_tmp = (float*)alloc(Z_ * 4);
  float* invsig = (float*)alloc(256);
  int* bar_cnt   = (int*)alloc(256);
  int* bar_sense = (int*)alloc(256);
  (void)in_sizes; (void)n_in; (void)out_size; (void)ws_size;

  initk<<<1, 64, 0, stream>>>(bar_cnt, bar_sense);
  mega<<<NWG, 256, 0, stream>>>(
      z, fc_w, fc_b, fc_u, w_ih, w_hh, b_ih, b_hh, lin_w, lin_b,
      w_ih_q, w_hhn_q, lin_w_q, lin_wT_q, fc_w_q, z_q, x0_q,
      Wsum_r, Wsum_z, Wn_c, Hhist, h_f32, outs,
      c0r, c0z, c0n, c1r, c1z, c1n, chn, dvec, sig_tmp, invsig,
      out, bar_cnt, bar_sense);
}

// Round 4
// 1036.145 us; speedup vs baseline: 1.0314x; 1.0314x over previous
//
#include <hip/hip_runtime.h>
#include <hip/hip_bf16.h>
#include <cstdint>
#include <cstddef>

#define B_  256
#define Z_  512
#define H_  2048
#define T_  16
#define H3_ 6144
#define NWG 256

using short8 = __attribute__((ext_vector_type(8))) short;
using bf16x8 = __attribute__((ext_vector_type(8))) __bf16;
using f32x4  = __attribute__((ext_vector_type(4))) float;

__device__ __forceinline__ f32x4 mfma_bf16(short8 a, short8 b, f32x4 c) {
  return __builtin_amdgcn_mfma_f32_16x16x32_bf16(
      __builtin_bit_cast(bf16x8, a), __builtin_bit_cast(bf16x8, b), c, 0, 0, 0);
}

__device__ __forceinline__ unsigned short f2bf(float f) {
  unsigned int u = __builtin_bit_cast(unsigned int, f);
  u = (u + 0x7FFFu + ((u >> 16) & 1u)) >> 16;
  return (unsigned short)u;
}

__device__ __forceinline__ float sigmoidf_(float x) { return 1.0f / (1.0f + __expf(-x)); }

// LDS XOR swizzle: tiles are [rows][64] bf16 (128 B rows = 8x16B chunks).
__device__ __forceinline__ int swz(int row, int chunk) {
  return row * 64 + ((chunk ^ (row & 7)) << 3);   // ushort element offset
}

// Storm-free grid barrier (sense reversal). Relaxed polls (sc1, no L2 inv),
// single release fence on arrival + acquire fence on exit. All WGs resident.
__device__ __forceinline__ void gbar(int* cnt, int* sense, int& ls) {
  __syncthreads();
  if (threadIdx.x == 0) {
    ls ^= 1;
    __builtin_amdgcn_fence(__ATOMIC_RELEASE, "agent");
    if (__hip_atomic_fetch_add(cnt, 1, __ATOMIC_RELAXED, __HIP_MEMORY_SCOPE_AGENT) == NWG - 1) {
      __hip_atomic_store(cnt, 0, __ATOMIC_RELAXED, __HIP_MEMORY_SCOPE_AGENT);
      __hip_atomic_store(sense, ls, __ATOMIC_RELEASE, __HIP_MEMORY_SCOPE_AGENT);
    } else {
      int spins = 0;
      while (true) {
        int v = ((++spins) & 63)
            ? __hip_atomic_load(sense, __ATOMIC_RELAXED, __HIP_MEMORY_SCOPE_AGENT)
            : __hip_atomic_load(sense, __ATOMIC_ACQUIRE, __HIP_MEMORY_SCOPE_AGENT);
        if (v == ls) break;
        __builtin_amdgcn_s_sleep(4);
      }
    }
    __builtin_amdgcn_fence(__ATOMIC_ACQUIRE, "agent");
  }
  __syncthreads();
}

// ---------------------------------------------------------------------------
// 64x64 GEMM tile, 512 threads (8 waves = 2 m-halves x 4 col-16s).
// C = A@B^T (+add)(+bias). smem: sA 8KB, sB 8KB.
// ---------------------------------------------------------------------------
__device__ __forceinline__ void dev_gemm64(
    unsigned short* sA, unsigned short* sB,
    const unsigned short* __restrict__ A,
    const unsigned short* __restrict__ Bw, int K,
    const float* __restrict__ addsrc, int add_ld,
    const float* __restrict__ bias,
    unsigned short* __restrict__ out_bf,
    float* __restrict__ out_f, int ldo, int mi, int ni)
{
  const int tid = threadIdx.x;
  const int m0 = mi * 64, n0 = ni * 64;
  const int wave = tid >> 6, lane = tid & 63;
  const int wr = wave & 1, wc = wave >> 1;
  const int q = lane >> 4, c16 = lane & 15;
  const int lr = tid >> 3, lc8 = tid & 7;
  f32x4 acc[2] = {};
  const size_t aoff = (size_t)(m0 + lr) * K;
  const size_t boff = (size_t)(n0 + lr) * K;
  uint4 ra, rb;
  const int nIter = K >> 6;
  int gc = lc8 * 8;
  ra = *(const uint4*)(A  + aoff + gc);
  rb = *(const uint4*)(Bw + boff + gc);
  for (int it = 0; it < nIter; ++it) {
    __syncthreads();
    *(uint4*)(sA + swz(lr, lc8)) = ra;
    *(uint4*)(sB + swz(lr, lc8)) = rb;
    __syncthreads();
    if (it + 1 < nIter) {
      gc = ((it + 1) << 6) + lc8 * 8;
      ra = *(const uint4*)(A  + aoff + gc);
      rb = *(const uint4*)(Bw + boff + gc);
    }
#pragma unroll
    for (int kk = 0; kk < 2; ++kk) {
      short8 af0 = *(const short8*)(sA + swz(wr * 32 + c16,      kk * 4 + q));
      short8 af1 = *(const short8*)(sA + swz(wr * 32 + 16 + c16, kk * 4 + q));
      short8 bf  = *(const short8*)(sB + swz(wc * 16 + c16,      kk * 4 + q));
      acc[0] = mfma_bf16(af0, bf, acc[0]);
      acc[1] = mfma_bf16(af1, bf, acc[1]);
    }
  }
#pragma unroll
  for (int i = 0; i < 2; ++i)
#pragma unroll
    for (int v = 0; v < 4; ++v) {
      const int row = m0 + wr * 32 + i * 16 + q * 4 + v;
      const int col = n0 + wc * 16 + c16;
      float val = acc[i][v];
      if (addsrc) val += addsrc[(size_t)row * add_ld + col];
      if (bias)   val += bias[col];
      if (out_f)  out_f[(size_t)row * ldo + col] = val;
      if (out_bf) out_bf[(size_t)row * ldo + col] = f2bf(val);
    }
}

// ---------------------------------------------------------------------------
// GRU tile: 512 threads (8 waves = 4 m-subs x 2 col-halves, all gates in-wave).
// M=64 rows x (4 gates x 32 cols). 2-deep register prefetch.
// smem: sA 8KB, sW 16KB.
// ---------------------------------------------------------------------------
__device__ __forceinline__ void dev_gru(
    unsigned short* sA, unsigned short* sW,
    const unsigned short* __restrict__ A, int K,
    const unsigned short* __restrict__ Wr,
    const unsigned short* __restrict__ Wz,
    const unsigned short* __restrict__ Wn,
    const unsigned short* __restrict__ Whn,
    const float* __restrict__ cr, const float* __restrict__ cz,
    const float* __restrict__ cn, const float* __restrict__ chn,
    const float* __restrict__ ascale_ptr, float hn_scale,
    const float* __restrict__ h_old,
    float* __restrict__ h_new,
    unsigned short* __restrict__ h_hist,
    int m0, int n0)
{
  const int tid = threadIdx.x;
  const int wave = tid >> 6, lane = tid & 63;
  const int ms = wave & 3, ch = wave >> 2;
  const int q = lane >> 4, c16 = lane & 15;
  const int lr = tid >> 3, lc8 = tid & 7;
  f32x4 acc[4] = {};
  const size_t aoff = (size_t)(m0 + lr) * K;
  const size_t woff = (size_t)(n0 + (lr & 31)) * K;
  const int glo = lr >> 5;  // rows 0-31 -> gates 0/2, 32-63 -> gates 1/3
  const unsigned short* Wlo = glo ? Wz  : Wr;
  const unsigned short* Whi = glo ? Whn : Wn;
  const int dlo = (glo ? 2048 : 0)    + swz(lr & 31, lc8);
  const int dhi = (glo ? 6144 : 4096) + swz(lr & 31, lc8);
  const int da  = swz(lr, lc8);
  uint4 ra[2], rlo[2], rhi[2];
  const int nIter = K >> 6;
  {
    int gc = lc8 * 8;
    ra[0]  = *(const uint4*)(A   + aoff + gc);
    rlo[0] = *(const uint4*)(Wlo + woff + gc);
    rhi[0] = *(const uint4*)(Whi + woff + gc);
    gc += 64;
    ra[1]  = *(const uint4*)(A   + aoff + gc);
    rlo[1] = *(const uint4*)(Wlo + woff + gc);
    rhi[1] = *(const uint4*)(Whi + woff + gc);
  }
  for (int it = 0; it < nIter; ++it) {
    const int s = it & 1;
    __syncthreads();
    *(uint4*)(sA + da)  = ra[s];
    *(uint4*)(sW + dlo) = rlo[s];
    *(uint4*)(sW + dhi) = rhi[s];
    __syncthreads();
    if (it + 2 < nIter) {
      const int gc = ((it + 2) << 6) + lc8 * 8;
      ra[s]  = *(const uint4*)(A   + aoff + gc);
      rlo[s] = *(const uint4*)(Wlo + woff + gc);
      rhi[s] = *(const uint4*)(Whi + woff + gc);
    }
#pragma unroll
    for (int kk = 0; kk < 2; ++kk) {
      short8 af = *(const short8*)(sA + swz(ms * 16 + c16, kk * 4 + q));
#pragma unroll
      for (int g = 0; g < 4; ++g) {
        short8 bf = *(const short8*)(sW + g * 2048 + swz(ch * 16 + c16, kk * 4 + q));
        acc[g] = mfma_bf16(af, bf, acc[g]);
      }
    }
  }
  const float as = ascale_ptr ? ascale_ptr[0] : 1.0f;
#pragma unroll
  for (int v = 0; v < 4; ++v) {
    const int row = m0 + ms * 16 + q * 4 + v;
    const int col = n0 + ch * 16 + c16;
    const float R   = sigmoidf_(as * acc[0][v] + cr[col]);
    const float U   = sigmoidf_(as * acc[1][v] + cz[col]);
    const float hnv = hn_scale * (as * acc[3][v]) + chn[col];
    const float Nv  = tanhf(as * acc[2][v] + cn[col] + R * hnv);
    const float ho  = h_old ? h_old[(size_t)row * H_ + col] : 0.0f;
    const float hv  = (1.0f - U) * Nv + U * ho;
    h_new[(size_t)row * H_ + col]  = hv;
    h_hist[(size_t)row * H_ + col] = f2bf(hv);
  }
}

__global__ void initk(int* cnt, int* sense) {
  if (threadIdx.x == 0) { *cnt = 0; *sense = 0; }
}

// ---------------------------------------------------------------------------
// Persistent mega-kernel: 256 WGs x 512 threads.
// ---------------------------------------------------------------------------
__global__ __launch_bounds__(512, 2) void mega(
    const float* __restrict__ z, const float* __restrict__ fc_w,
    const float* __restrict__ fc_b, const float* __restrict__ fc_u,
    const float* __restrict__ w_ih, const float* __restrict__ w_hh,
    const float* __restrict__ b_ih, const float* __restrict__ b_hh,
    const float* __restrict__ lin_w, const float* __restrict__ lin_b,
    unsigned short* w_ih_q, unsigned short* w_hhn_q, unsigned short* lin_w_q,
    unsigned short* lin_wT_q, unsigned short* fc_w_q, unsigned short* z_q,
    unsigned short* x0_q, unsigned short* Wsum_r, unsigned short* Wsum_z,
    unsigned short* Wn_c, unsigned short* Hhist, float* h_f32,
    float* outs, float* c0r, float* c0z, float* c0n, float* c1r, float* c1z,
    float* c1n, float* chn, float* dvec, float* evec, float* sig_tmp,
    float* invsig, float* out, int* bar_cnt, int* bar_sense)
{
  __shared__ __align__(16) unsigned char SMEM[24576];
  unsigned short* sAg = (unsigned short*)SMEM;          // 8KB
  unsigned short* sWg = (unsigned short*)(SMEM + 8192); // 16KB
  const int bid = blockIdx.x, tid = threadIdx.x;
  int ls = 0;

  // ---------------- Phase A: quant + transpose + dots -----------------------
  {
    const int gtid = bid * 512 + tid;
    // float4 ranges: z 32768 | fc_w 65536 | w_ih 786432 | w_hhn 1048576 | lin_w 262144
    for (int i = gtid; i < 2195456; i += NWG * 512) {
      const float4* src; ushort4* dst; int idx;
      if (i < 32768)        { src = (const float4*)z;     dst = (ushort4*)z_q;     idx = i; }
      else if (i < 98304)   { src = (const float4*)fc_w;  dst = (ushort4*)fc_w_q;  idx = i - 32768; }
      else if (i < 884736)  { src = (const float4*)w_ih;  dst = (ushort4*)w_ih_q;  idx = i - 98304; }
      else if (i < 1933312) { src = (const float4*)(w_hh + (size_t)2 * H_ * H_);
                              dst = (ushort4*)w_hhn_q;    idx = i - 884736; }
      else                  { src = (const float4*)lin_w; dst = (ushort4*)lin_w_q; idx = i - 1933312; }
      float4 v = src[idx];
      ushort4 o; o.x = f2bf(v.x); o.y = f2bf(v.y); o.z = f2bf(v.z); o.w = f2bf(v.w);
      dst[idx] = o;
    }
    // transq: lin_w [512][2048] -> lin_wT_q [2048][512] bf16, 1024 tiles of 32x32
    float* tile = (float*)SMEM;  // [32][33]
    const int tx = tid & 31, ty = tid >> 5;   // ty in [0,16)
    for (int tt = bid; tt < 1024; tt += NWG) {
      const int bx = tt >> 4, by = tt & 15;
      const int k0 = bx * 32, z0 = by * 32;
      __syncthreads();
#pragma unroll
      for (int j = 0; j < 2; ++j)
        tile[(ty + j * 16) * 33 + tx] = lin_w[(size_t)(z0 + ty + j * 16) * H_ + k0 + tx];
      __syncthreads();
#pragma unroll
      for (int j = 0; j < 2; ++j)
        lin_wT_q[(size_t)(k0 + ty + j * 16) * Z_ + z0 + tx] = f2bf(tile[tx * 33 + ty + j * 16]);
    }
    // dots: dvec[row]=dot(w_ih[row],lin_b), evec[row]=dot(w_ih[row],fc_b)
    const int wave = tid >> 6, lane = tid & 63;
    for (int row = bid * 8 + wave; row < H3_; row += 2048) {
      float s1 = 0.f, s2 = 0.f;
      for (int c = lane; c < Z_; c += 64) {
        const float w = w_ih[(size_t)row * Z_ + c];
        s1 += w * lin_b[c]; s2 += w * fc_b[c];
      }
#pragma unroll
      for (int off = 32; off > 0; off >>= 1) {
        s1 += __shfl_down(s1, off); s2 += __shfl_down(s2, off);
      }
      if (lane == 0) { dvec[row] = s1; evec[row] = s2; }
    }
  }
  gbar(bar_cnt, bar_sense, ls);

  // ---- Phase B: WG0 sigma chain || {Wsum GEMMs, x0' GEMM, consts} ----------
  if (bid == 0) {
    float* red = (float*)SMEM;  // 512 floats
    float a = 0.f;
    for (int r = 0; r < Z_; ++r) a += fc_w[(size_t)r * Z_ + tid] * fc_u[r];
    sig_tmp[tid] = a;
    red[tid] = a * a;
    __syncthreads();
    for (int s = 256; s > 0; s >>= 1) { if (tid < s) red[tid] += red[tid + s]; __syncthreads(); }
    const float invn = 1.0f / (sqrtf(red[0]) + 1e-12f);
    __syncthreads();
    float b = 0.f;
    for (int c = 0; c < Z_; ++c) b += fc_w[(size_t)tid * Z_ + c] * sig_tmp[c];
    b *= invn;
    red[tid] = b * b;
    __syncthreads();
    for (int s = 256; s > 0; s >>= 1) { if (tid < s) red[tid] += red[tid + s]; __syncthreads(); }
    if (tid == 0) {
      const float s2 = red[0];
      invsig[0] = (sqrtf(s2) + 1e-12f) / s2;   // 1/sigma
    }
  } else {
    for (int j = bid - 1; j < 3108; j += NWG - 1) {
      if (j < 3072) {
        const int g = j >> 10, tt = j & 1023, mi = tt >> 5, ni = tt & 31;
        const float* adds = (g < 2) ? (w_hh + (size_t)g * H_ * H_) : nullptr;
        unsigned short* outw = (g == 0) ? Wsum_r : (g == 1) ? Wsum_z : Wn_c;
        dev_gemm64(sAg, sWg, w_ih_q + (size_t)g * H_ * Z_, lin_wT_q, Z_,
                   adds, H_, nullptr, outw, nullptr, H_, mi, ni);
      } else if (j < 3104) {
        const int tt = j - 3072, mi = tt >> 3, ni = tt & 7;  // x0' unscaled
        dev_gemm64(sAg, sWg, z_q, fc_w_q, Z_, nullptr, 0, nullptr,
                   x0_q, nullptr, Z_, mi, ni);
      } else {
        const int jj = (j - 3104) * 512 + tid;
        const float br = b_ih[jj], bz = b_ih[H_ + jj], bn = b_ih[2 * H_ + jj];
        const float hr = b_hh[jj], hz = b_hh[H_ + jj], hn = b_hh[2 * H_ + jj];
        c0r[jj] = br + hr + evec[jj];
        c0z[jj] = bz + hz + evec[H_ + jj];
        c0n[jj] = bn + evec[2 * H_ + jj];
        chn[jj] = hn;
        c1r[jj] = br + hr + dvec[jj];
        c1z[jj] = bz + hz + dvec[H_ + jj];
        c1n[jj] = bn + dvec[2 * H_ + jj];
      }
    }
  }
  gbar(bar_cnt, bar_sense, ls);

  // ---------------- Phase D: 16 GRU steps -----------------------------------
  {
    const int xcd = bid & 7, rest = bid >> 3;
    const int m_idx = rest & 3, grp = rest >> 2;
    const int n_idx = grp * 8 + xcd;
    const int m0 = m_idx * 64, n0 = n_idx * 32;
#pragma unroll 1
    for (int t = 0; t < T_; ++t) {
      const bool first = (t == 0);
      const unsigned short* Aq = first ? x0_q : (Hhist + (size_t)(t - 1) * B_ * H_);
      const int K = first ? Z_ : H_;
      const unsigned short* Wr = first ? w_ih_q : Wsum_r;
      const unsigned short* Wz = first ? (w_ih_q + (size_t)H_ * Z_) : Wsum_z;
      const unsigned short* Wn = first ? (w_ih_q + (size_t)2 * H_ * Z_) : Wn_c;
      const unsigned short* Wh = first ? w_ih_q : w_hhn_q;  // dummy at t=0
      const float* pcr = first ? c0r : c1r;
      const float* pcz = first ? c0z : c1z;
      const float* pcn = first ? c0n : c1n;
      const float* asc = first ? invsig : nullptr;
      const float hscale = first ? 0.0f : 1.0f;
      const float* hold = first ? nullptr : (h_f32 + (size_t)((t - 1) & 1) * B_ * H_);
      float* hnew = h_f32 + (size_t)(t & 1) * B_ * H_;
      unsigned short* hh = Hhist + (size_t)t * B_ * H_;
      dev_gru(sAg, sWg, Aq, K, Wr, Wz, Wn, Wh, pcr, pcz, pcn, chn,
              asc, hscale, hold, hnew, hh, m0, n0);
      gbar(bar_cnt, bar_sense, ls);
    }
  }

  // ---------------- Phase E: outs = Hhist @ lin_w^T + lin_b -----------------
#pragma unroll 1
  for (int j = bid; j < 512; j += NWG) {
    const int mi = j >> 3, ni = j & 7;
    dev_gemm64(sAg, sWg, Hhist, lin_w_q, H_, nullptr, 0, lin_b,
               nullptr, outs, Z_, mi, ni);
  }
  gbar(bar_cnt, bar_sense, ls);

  // ---------------- Phase F: BN over batch + transpose ----------------------
  if (bid < 128) {
    float* s_sum  = (float*)SMEM;        // [8][64]
    float* s_sq   = s_sum + 512;         // [8][64]
    float* s_mean = s_sq + 512;          // [64]
    float* s_inv  = s_mean + 64;         // [64]
    const int t = bid >> 3, zb = bid & 7;
    const int zl = tid & 63, bp = tid >> 6;
    const int zc = zb * 64 + zl;
    float sum = 0.f, sq = 0.f;
    for (int b = bp * 32; b < bp * 32 + 32; ++b) {
      float v = outs[(size_t)(t * 256 + b) * Z_ + zc];
      sum += v; sq += v * v;
    }
    s_sum[bp * 64 + zl] = sum; s_sq[bp * 64 + zl] = sq;
    __syncthreads();
    if (bp == 0) {
      float S = 0.f, Q = 0.f;
#pragma unroll
      for (int p = 0; p < 8; ++p) { S += s_sum[p * 64 + zl]; Q += s_sq[p * 64 + zl]; }
      float mean = S * (1.0f / 256.0f);
      float var  = Q * (1.0f / 256.0f) - mean * mean;
      s_mean[zl] = mean;
      s_inv[zl]  = rsqrtf(var + 1e-5f);
    }
    __syncthreads();
    const float mean = s_mean[zl], inv = s_inv[zl];
    for (int b = bp * 32; b < bp * 32 + 32; ++b) {
      float v = outs[(size_t)(t * 256 + b) * Z_ + zc];
      out[(size_t)(b * T_ + t) * Z_ + zc] = (v - mean) * inv;
    }
  }
}

// ---------------------------------------------------------------------------
extern "C" void kernel_launch(void* const* d_in, const int* in_sizes, int n_in,
                              void* d_out, int out_size, void* d_ws, size_t ws_size,
                              hipStream_t stream) {
  const float* z     = (const float*)d_in[0];
  const float* fc_w  = (const float*)d_in[1];
  const float* fc_b  = (const float*)d_in[2];
  const float* fc_u  = (const float*)d_in[3];
  const float* w_ih  = (const float*)d_in[4];
  const float* w_hh  = (const float*)d_in[5];
  const float* b_ih  = (const float*)d_in[6];
  const float* b_hh  = (const float*)d_in[7];
  const float* lin_w = (const float*)d_in[8];
  const float* lin_b = (const float*)d_in[9];
  float* out = (float*)d_out;

  char* ws = (char*)d_ws;
  size_t off = 0;
  auto alloc = [&](size_t bytes) -> void* {
    off = (off + 255) & ~(size_t)255;
    void* p = ws + off;
    off += bytes;
    return p;
  };
  unsigned short* w_ih_q   = (unsigned short*)alloc((size_t)H3_ * Z_ * 2);
  unsigned short* w_hhn_q  = (unsigned short*)alloc((size_t)H_ * H_ * 2);
  unsigned short* lin_w_q  = (unsigned short*)alloc((size_t)Z_ * H_ * 2);
  unsigned short* lin_wT_q = (unsigned short*)alloc((size_t)Z_ * H_ * 2);
  unsigned short* fc_w_q   = (unsigned short*)alloc((size_t)Z_ * Z_ * 2);
  unsigned short* z_q      = (unsigned short*)alloc((size_t)B_ * Z_ * 2);
  unsigned short* x0_q     = (unsigned short*)alloc((size_t)B_ * Z_ * 2);
  unsigned short* Wsum_r   = (unsigned short*)alloc((size_t)H_ * H_ * 2);
  unsigned short* Wsum_z   = (unsigned short*)alloc((size_t)H_ * H_ * 2);
  unsigned short* Wn_c     = (unsigned short*)alloc((size_t)H_ * H_ * 2);
  unsigned short* Hhist    = (unsigned short*)alloc((size_t)T_ * B_ * H_ * 2);
  float* h_f32 = (float*)alloc((size_t)2 * B_ * H_ * 4);
  float* outs  = (float*)alloc((size_t)T_ * B_ * Z_ * 4);
  float* c0r = (float*)alloc(H_ * 4);
  float* c0z = (float*)alloc(H_ * 4);
  float* c0n = (float*)alloc(H_ * 4);
  float* c1r = (float*)alloc(H_ * 4);
  float* c1z = (float*)alloc(H_ * 4);
  float* c1n = (float*)alloc(H_ * 4);
  float* chn = (float*)alloc(H_ * 4);
  float* dvec = (float*)alloc(H3_ * 4);
  float* evec = (float*)alloc(H3_ * 4);
  float* sig_tmp = (float*)alloc(Z_ * 4);
  float* invsig = (float*)alloc(256);
  int* bar_cnt   = (int*)alloc(256);
  int* bar_sense = (int*)alloc(256);
  (void)in_sizes; (void)n_in; (void)out_size; (void)ws_size;

  initk<<<1, 64, 0, stream>>>(bar_cnt, bar_sense);
  mega<<<NWG, 512, 0, stream>>>(
      z, fc_w, fc_b, fc_u, w_ih, w_hh, b_ih, b_hh, lin_w, lin_b,
      w_ih_q, w_hhn_q, lin_w_q, lin_wT_q, fc_w_q, z_q, x0_q,
      Wsum_r, Wsum_z, Wn_c, Hhist, h_f32, outs,
      c0r, c0z, c0n, c1r, c1z, c1n, chn, dvec, evec, sig_tmp, invsig,
      out, bar_cnt, bar_sense);
}